// Round 2
// baseline (346.587 us; speedup 1.0000x reference)
//
#include <hip/hip_runtime.h>
#include <math.h>

// Gaussian blur, (64, 512, 512, 3) f32 NHWC, per-batch sigma.
// Reference's kernel k[b,di,dj] depends only on dj (xs broadcast bug in ref),
// so conv = vertical 3-row box sum, then horizontal [w0, w1, w0] over pixels
// (stride 3 floats in channel-interleaved layout).
//   s  = 3*stds[b];  e = exp(-1/s^2)
//   w1 = 1/(3*(1+2e));  w0 = e*w1
//
// V2: strip-per-block with register-rolling vertical window.
//   V1 read every row 3x (one block per row -> rows i-1,i,i+1 each block):
//   576 MiB of loads + 192 MiB stores ~= 120 us at 6.7 TB/s. This version
//   loads each row once (34/32 = 1.06x halo overfetch), prefetches row j+2
//   one barrier ahead, double-buffers the LDS colsum row (1 sync/row), and
//   streams the output with nontemporal stores. Compulsory traffic 402 MB
//   -> ~63 us roofline.
//
// V2b: use a native clang ext_vector_type instead of HIP float4 —
//   __builtin_nontemporal_store rejects HIP_vector_type wrappers.

constexpr int Wd     = 512;
constexpr int Hd     = 512;
constexpr int Cd     = 3;
constexpr int ROWF   = Wd * Cd;        // 1536 floats per row
constexpr int TPB    = ROWF / 4;       // 384 threads, one 16B vector each
constexpr int RPB    = 32;             // rows per block
constexpr int STRIPS = Hd / RPB;       // 16 strips per image

using f4 = __attribute__((ext_vector_type(4))) float;

__device__ __forceinline__ f4 f4zero() { return (f4){0.f, 0.f, 0.f, 0.f}; }

__global__ __launch_bounds__(TPB) void gauss_strip_kernel(
    const float* __restrict__ x,
    const float* __restrict__ stds,
    float* __restrict__ out)
{
    __shared__ f4 cs[2][TPB + 2];   // double-buffered colsum row + zero halo

    const int t = threadIdx.x;
    const int s = blockIdx.x % STRIPS;  // strip index within image
    const int b = blockIdx.x / STRIPS;  // batch

    const float sg = stds[b] * 3.0f;
    const float e  = expf(-1.0f / (sg * sg));
    const float w1 = 1.0f / (3.0f * (1.0f + 2.0f * e));
    const float w0 = e * w1;

    const size_t imgbase = (size_t)b * Hd * ROWF;
    const float* px = x   + imgbase + (size_t)t * 4;
    float*       po = out + imgbase + (size_t)t * 4;

    const int r0 = s * RPB;

    // rolling vertical window: ra = row j-1, rb = row j, rc = row j+1
    f4 ra = (r0 > 0) ? *(const f4*)(px + (size_t)(r0 - 1) * ROWF) : f4zero();
    f4 rb = *(const f4*)(px + (size_t)r0 * ROWF);
    f4 rc = *(const f4*)(px + (size_t)(r0 + 1) * ROWF);  // r0+1 <= 481, always in-bounds

    if (t == 0) {
        cs[0][0] = cs[0][TPB + 1] = f4zero();
        cs[1][0] = cs[1][TPB + 1] = f4zero();
    }

    #pragma unroll 2
    for (int j = r0; j < r0 + RPB; ++j) {
        // prefetch row j+2 one full iteration (incl. barrier) ahead of use
        f4 rn = (j + 2 < Hd) ? *(const f4*)(px + (size_t)(j + 2) * ROWF)
                             : f4zero();

        f4 m = ra + rb + rc;                 // vertical 3-row box sum

        f4* buf = cs[j & 1];
        buf[t + 1] = m;
        __syncthreads();

        const f4 p = buf[t];                 // colsum[f-4 .. f-1]
        const f4 n = buf[t + 2];             // colsum[f+4 .. f+7]

        // out[f+k] = w1*colsum[f+k] + w0*(colsum[f+k-3] + colsum[f+k+3])
        f4 o;
        o.x = w1 * m.x + w0 * (p.y + m.w);
        o.y = w1 * m.y + w0 * (p.z + n.x);
        o.z = w1 * m.z + w0 * (p.w + n.y);
        o.w = w1 * m.w + w0 * (m.x + n.z);

        __builtin_nontemporal_store(o, (f4*)(po + (size_t)j * ROWF));

        ra = rb; rb = rc; rc = rn;
    }
}

extern "C" void kernel_launch(void* const* d_in, const int* in_sizes, int n_in,
                              void* d_out, int out_size, void* d_ws, size_t ws_size,
                              hipStream_t stream) {
    const float* x    = (const float*)d_in[0];
    const float* stds = (const float*)d_in[1];
    float* out        = (float*)d_out;

    const int nblocks = 64 * STRIPS;   // one block per (batch, 32-row strip) = 1024
    gauss_strip_kernel<<<nblocks, TPB, 0, stream>>>(x, stds, out);
}